// Round 2
// baseline (287.217 us; speedup 1.0000x reference)
//
#include <hip/hip_runtime.h>
#include <hip/hip_fp16.h>
#include <math.h>

// ---------------------------------------------------------------------------
// GATv2 x2 layers, N=50000, D=128, HID=128, heads 4 then 1, E=800000 (+ self loops)
//   1) CSR build by dst via direct atomic build: count -> scan -> scatter
//      (order within a node's list is nondeterministic, same as the previous
//       LDS-atomic fine sort — summation class unchanged)
//   2) fp16 MFMA dual GEMM with LDS-staged B; layer-1 converts fp32 X in-register
//   3) edge aggregation: quadrant-per-edge, 4 gathers in flight, packed-fp16
//      leaky+dot, DPP logit reduction, exp-sum softmax (no running max)
//   Overlap: [count | convert], [scan | gemm1a], [scatter | gemm1b].
// ---------------------------------------------------------------------------

#define NEG_SLOPE 0.2f
#define COUNTB 128   // blocks for the count phase
#define SCATB  128   // blocks for the scatter phase

typedef _Float16 half8 __attribute__((ext_vector_type(8)));
typedef _Float16 half2v __attribute__((ext_vector_type(2)));
typedef float floatx4 __attribute__((ext_vector_type(4)));

#if defined(__has_builtin)
#if __has_builtin(__builtin_amdgcn_fdot2)
#define HAVE_FDOT2 1
#endif
#endif

// DPP cross-lane add helpers (VALU pipe, no LDS traffic)
template <int CTRL>
__device__ __forceinline__ float dppmov(float x) {
    int xi = __builtin_bit_cast(int, x);
    int r  = __builtin_amdgcn_update_dpp(0, xi, CTRL, 0xF, 0xF, true);
    return __builtin_bit_cast(float, r);
}
#define DPP_XOR1  0xB1   // quad_perm [1,0,3,2]
#define DPP_XOR2  0x4E   // quad_perm [2,3,0,1]
#define DPP_HMIRR 0x141  // row_half_mirror (lane^7 within 8)
#define DPP_MIRR  0x140  // row_mirror      (lane^15 within 16)

// ---------------- device bodies ----------------------------------------------

// count: per-dst degree histogram via global atomics (no-return -> fire&forget)
__device__ __forceinline__ void count_body(int b, const int* __restrict__ dstA,
                                           int* __restrict__ counts, int E, int Et) {
    const int STR = COUNTB * 256;
    for (int e = b * 256 + threadIdx.x; e < Et; e += STR) {
        int d = (e < E) ? dstA[e] : (e - E);
        atomicAdd(&counts[d], 1);
    }
}

// convert: Wt[c][k] fp16 transposed dual for both layers + att1/att2 -> fp16
__device__ __forceinline__ void convert_body(int t,
        const float* __restrict__ Wl1, const float* __restrict__ Wr1,
        const float* __restrict__ Wl2, const float* __restrict__ Wr2,
        const float* __restrict__ att1, const float* __restrict__ att2,
        _Float16* __restrict__ Wt1, _Float16* __restrict__ Wt2,
        _Float16* __restrict__ attH) {
    if (t < 65536) {
        int layer = t >> 15;
        int id = t & 32767;
        int c = id >> 7, k = id & 127;
        const float* Wl = layer ? Wl2 : Wl1;
        const float* Wr = layer ? Wr2 : Wr1;
        _Float16* Wt = layer ? Wt2 : Wt1;
        float v = (c < 128) ? Wl[(size_t)k * 128 + c] : Wr[(size_t)k * 128 + (c - 128)];
        Wt[(size_t)c * 128 + k] = (_Float16)v;
    } else {
        int id = t - 65536;          // 0..255
        if (id < 256) {
            float v = (id < 128) ? att1[id] : att2[id - 128];
            attH[id] = (_Float16)v;
        }
    }
}

// scan: exclusive scan of counts[0..npad) -> rowptr and cursor (one 256-thr block).
// counts padded with zeros to npad = 1024*ceil(n/1024), so rowptr[i>=n] = Et.
__device__ __forceinline__ void scan_body(const int* __restrict__ counts,
        int* __restrict__ rowptr, int* __restrict__ cursor, int n, int Et) {
    __shared__ int wsum[4];
    int t = threadIdx.x;          // 0..255
    int lane = t & 63, w = t >> 6;
    int c4 = (n + 1023) >> 10;    // int4s per thread
    const int4* cp = (const int4*)counts + (size_t)t * c4;
    int local = 0;
    for (int j = 0; j < c4; ++j) {
        int4 v = cp[j];
        local += v.x + v.y + v.z + v.w;
    }
    int x = local;
    #pragma unroll
    for (int off = 1; off < 64; off <<= 1) {
        int y = __shfl_up(x, off, 64);
        if (lane >= off) x += y;
    }
    if (lane == 63) wsum[w] = x;
    __syncthreads();
    int woff = 0;
    for (int i = 0; i < w; ++i) woff += wsum[i];
    int run = woff + x - local;   // exclusive prefix of this thread's first value
    int4* rp = (int4*)rowptr + (size_t)t * c4;
    int4* qp = (int4*)cursor + (size_t)t * c4;
    for (int j = 0; j < c4; ++j) {
        int4 v = cp[j];
        int4 o;
        o.x = run;
        o.y = run + v.x;
        o.z = o.y + v.y;
        o.w = o.z + v.z;
        run = o.w + v.w;
        rp[j] = o;
        qp[j] = o;
    }
    if (t == 255) rowptr[n] = Et;  // also produced by padded prefix; benign dup
}

// scatter: srcs[atomicAdd(&cursor[dst])] = src; 4-way unrolled so 4 returning
// atomics are in flight per thread (hides L2 atomic round-trip).
__device__ __forceinline__ void scatter_body(int b, const int* __restrict__ srcA,
        const int* __restrict__ dstA, int* __restrict__ cursor,
        int* __restrict__ srcs, int E, int Et) {
    const int STR = SCATB * 256;
    int e = b * 256 + threadIdx.x;
    for (; e + 3 * STR < Et; e += 4 * STR) {
        int ea = e, eb = e + STR, ec = e + 2 * STR, ed = e + 3 * STR;
        int s0, d0, s1, d1, s2, d2, s3, d3;
        if (ea < E) { s0 = srcA[ea]; d0 = dstA[ea]; } else { s0 = ea - E; d0 = s0; }
        if (eb < E) { s1 = srcA[eb]; d1 = dstA[eb]; } else { s1 = eb - E; d1 = s1; }
        if (ec < E) { s2 = srcA[ec]; d2 = dstA[ec]; } else { s2 = ec - E; d2 = s2; }
        if (ed < E) { s3 = srcA[ed]; d3 = dstA[ed]; } else { s3 = ed - E; d3 = s3; }
        int p0 = atomicAdd(&cursor[d0], 1);
        int p1 = atomicAdd(&cursor[d1], 1);
        int p2 = atomicAdd(&cursor[d2], 1);
        int p3 = atomicAdd(&cursor[d3], 1);
        srcs[p0] = s0;
        srcs[p1] = s1;
        srcs[p2] = s2;
        srcs[p3] = s3;
    }
    for (; e < Et; e += STR) {
        int s, d;
        if (e < E) { s = srcA[e]; d = dstA[e]; } else { s = e - E; d = s; }
        int p = atomicAdd(&cursor[d], 1);
        srcs[p] = s;
    }
}

// gemm: C[n x 256] = A[n x 128] @ W[128 x 256]; cols 0-127 -> outL (fp16),
// 128-255 -> outR (fp16). B (Wt, transposed) staged in LDS.
#define BPAD 136   // LDS row length in halves (128 + 8 pad)

template <bool AF32>
__device__ __forceinline__ void gemm_body(int bid, const void* __restrict__ Av,
        const _Float16* __restrict__ Bt, _Float16* __restrict__ outL,
        _Float16* __restrict__ outR, int n) {
    __shared__ _Float16 sB[256 * BPAD];
    int tid = threadIdx.x;
    {
        int c0 = (tid & 15) * 8;
        int r0 = tid >> 4;
        #pragma unroll
        for (int i = 0; i < 16; ++i) {
            int r = r0 + i * 16;
            *(half8*)(sB + r * BPAD + c0) = *(const half8*)(Bt + (size_t)r * 128 + c0);
        }
    }
    int wave = tid >> 6;
    int lane = tid & 63;
    int ln = lane & 15;
    int q  = lane >> 4;
    int row0 = bid * 64 + wave * 16;

    int arow = row0 + ln;
    if (arow >= n) arow = n - 1;             // clamp; stores guarded below
    half8 a0, a1, a2, a3;
    if (AF32) {
        const float* ap = (const float*)Av + (size_t)arow * 128 + q * 8;
        #pragma unroll
        for (int g = 0; g < 4; ++g) {
            float4 f0 = *(const float4*)(ap + g * 32);
            float4 f1 = *(const float4*)(ap + g * 32 + 4);
            half8 h;
            h[0] = (_Float16)f0.x; h[1] = (_Float16)f0.y;
            h[2] = (_Float16)f0.z; h[3] = (_Float16)f0.w;
            h[4] = (_Float16)f1.x; h[5] = (_Float16)f1.y;
            h[6] = (_Float16)f1.z; h[7] = (_Float16)f1.w;
            if (g == 0) a0 = h; else if (g == 1) a1 = h;
            else if (g == 2) a2 = h; else a3 = h;
        }
    } else {
        const _Float16* ap = (const _Float16*)Av + (size_t)arow * 128 + q * 8;
        a0 = *(const half8*)(ap);
        a1 = *(const half8*)(ap + 32);
        a2 = *(const half8*)(ap + 64);
        a3 = *(const half8*)(ap + 96);
    }

    __syncthreads();

    floatx4 acc[16];
    #pragma unroll
    for (int ct = 0; ct < 16; ++ct) {
        const _Float16* bp = sB + (ct * 16 + ln) * BPAD + q * 8;
        half8 b0 = *(const half8*)(bp);
        half8 b1 = *(const half8*)(bp + 32);
        half8 b2 = *(const half8*)(bp + 64);
        half8 b3 = *(const half8*)(bp + 96);
        floatx4 c = {0.f, 0.f, 0.f, 0.f};
        c = __builtin_amdgcn_mfma_f32_16x16x32_f16(a0, b0, c, 0, 0, 0);
        c = __builtin_amdgcn_mfma_f32_16x16x32_f16(a1, b1, c, 0, 0, 0);
        c = __builtin_amdgcn_mfma_f32_16x16x32_f16(a2, b2, c, 0, 0, 0);
        c = __builtin_amdgcn_mfma_f32_16x16x32_f16(a3, b3, c, 0, 0, 0);
        acc[ct] = c;
    }

    #pragma unroll
    for (int ct = 0; ct < 16; ++ct) {
        int col = ct * 16 + ln;
        #pragma unroll
        for (int r = 0; r < 4; ++r) {
            int grow = row0 + q * 4 + r;
            if (grow < n) {
                _Float16 v = (_Float16)acc[ct][r];
                if (ct < 8) outL[(size_t)grow * 128 + col] = v;
                else        outR[(size_t)grow * 128 + (col - 128)] = v;
            }
        }
    }
}

// ---------------- fused kernels ----------------------------------------------

// fused_pre: blocks 0..COUNTB-1 count degrees; blocks COUNTB.. convert weights
__global__ __launch_bounds__(256)
void fused_pre(const int* __restrict__ dstA, int* __restrict__ counts,
               int E, int Et,
               const float* __restrict__ Wl1, const float* __restrict__ Wr1,
               const float* __restrict__ Wl2, const float* __restrict__ Wr2,
               const float* __restrict__ att1, const float* __restrict__ att2,
               _Float16* __restrict__ Wt1, _Float16* __restrict__ Wt2,
               _Float16* __restrict__ attH) {
    if (blockIdx.x < COUNTB) {
        count_body(blockIdx.x, dstA, counts, E, Et);
    } else {
        int t = (blockIdx.x - COUNTB) * 256 + threadIdx.x;
        convert_body(t, Wl1, Wr1, Wl2, Wr2, att1, att2, Wt1, Wt2, attH);
    }
}

// fused_scan_gemm: block 0 = degree scan -> rowptr+cursor; blocks 1.. =
// first half of layer-1 GEMM (A = fp32 X). Hides the scan under the GEMM.
__global__ __launch_bounds__(256)
void fused_scan_gemm(const int* __restrict__ counts, int* __restrict__ rowptr,
                     int* __restrict__ cursor,
                     const float* __restrict__ X, const _Float16* __restrict__ Wt1,
                     _Float16* __restrict__ outL, _Float16* __restrict__ outR,
                     int n, int Et) {
    if (blockIdx.x == 0) {
        scan_body(counts, rowptr, cursor, n, Et);
    } else {
        gemm_body<true>(blockIdx.x - 1, X, Wt1, outL, outR, n);
    }
}

// fused_scatter_gemm: blocks 0..SCATB-1 scatter srcs; blocks SCATB.. = second
// half of layer-1 GEMM
__global__ __launch_bounds__(256)
void fused_scatter_gemm(const int* __restrict__ srcA, const int* __restrict__ dstA,
                        int* __restrict__ cursor, int* __restrict__ srcs,
                        int E, int Et, int gemm_base,
                        const float* __restrict__ X, const _Float16* __restrict__ Wt1,
                        _Float16* __restrict__ outL, _Float16* __restrict__ outR,
                        int n) {
    if (blockIdx.x < SCATB) {
        scatter_body(blockIdx.x, srcA, dstA, cursor, srcs, E, Et);
    } else {
        gemm_body<true>(blockIdx.x - SCATB + gemm_base, X, Wt1, outL, outR, n);
    }
}

// layer-2 GEMM standalone
__global__ __launch_bounds__(256)
void gemm_l2(const _Float16* __restrict__ A, const _Float16* __restrict__ Bt,
             _Float16* __restrict__ outL, _Float16* __restrict__ outR, int n) {
    gemm_body<false>(blockIdx.x, A, Bt, outL, outR, n);
}

// ---------------- edge aggregation: quadrant-per-edge, 4-deep MLP ------------
// Wave = 4 quadrants x 16 lanes; quadrant q handles one edge per proc; lane ln
// holds channels ln*8..+7 (16B gathers). 16-edge inner step = 4 independent
// gathers in flight. leaky+dot packed fp16 + v_dot2_f32_f16; DPP reduction.

template <bool LAYER1>
__global__ __launch_bounds__(256)
void edge_aggregate(const _Float16* __restrict__ xl, const _Float16* __restrict__ xr,
                    const _Float16* __restrict__ attH, const float* __restrict__ bias,
                    const int* __restrict__ rowptr, const int* __restrict__ srcs,
                    void* __restrict__ outv, int n) {
    int node = blockIdx.x * (blockDim.x >> 6) + (threadIdx.x >> 6);
    int lane = threadIdx.x & 63;
    if (node >= n) return;
    int ln = lane & 15;
    int q  = lane >> 4;
    int c0 = ln * 8;

    half8 xrh = *(const half8*)(xr + (size_t)node * 128 + c0);
    half8 ahh = *(const half8*)(attH + c0);

    float acc[8] = {0.f, 0.f, 0.f, 0.f, 0.f, 0.f, 0.f, 0.f};
    float l = 0.f;

    auto proc = [&](half8 vh, bool valid) {
        half8 e  = vh + xrh;                                   // pk_add x4
        half8 es = e * (_Float16)NEG_SLOPE;                    // pk_mul x4
        half8 lr = __builtin_elementwise_max(e, es);           // pk_max x4
        float p = 0.f;
        #pragma unroll
        for (int k = 0; k < 4; ++k) {
            half2v ee = { lr[2 * k], lr[2 * k + 1] };
            half2v aa = { ahh[2 * k], ahh[2 * k + 1] };
#ifdef HAVE_FDOT2
            p = __builtin_amdgcn_fdot2(ee, aa, p, false);      // v_dot2_f32_f16
#else
            p = fmaf((float)ee[0], (float)aa[0], p);
            p = fmaf((float)ee[1], (float)aa[1], p);
#endif
        }
        p += dppmov<DPP_XOR1>(p);
        p += dppmov<DPP_XOR2>(p);
        if (!LAYER1) { p += dppmov<DPP_HMIRR>(p); p += dppmov<DPP_MIRR>(p); }
        float pe = __expf(p);
        if (!valid) pe = 0.f;
        l += pe;
        #pragma unroll
        for (int k = 0; k < 8; ++k) acc[k] = fmaf(pe, (float)vh[k], acc[k]);
    };

    int jb = rowptr[node], je = rowptr[node + 1];
    for (int base = jb; base < je; base += 64) {
        int idx = base + lane;
        int myS = (idx < je) ? srcs[idx] : 0;
        int cnt = min(64, je - base);
        int t = 0;
        for (; t + 16 <= cnt; t += 16) {
            int s0 = __shfl(myS, t + q, 64);
            int s1 = __shfl(myS, t + 4 + q, 64);
            int s2 = __shfl(myS, t + 8 + q, 64);
            int s3 = __shfl(myS, t + 12 + q, 64);
            half8 v0 = *(const half8*)(xl + (size_t)s0 * 128 + c0);
            half8 v1 = *(const half8*)(xl + (size_t)s1 * 128 + c0);
            half8 v2 = *(const half8*)(xl + (size_t)s2 * 128 + c0);
            half8 v3 = *(const half8*)(xl + (size_t)s3 * 128 + c0);
            proc(v0, true); proc(v1, true); proc(v2, true); proc(v3, true);
        }
        for (; t < cnt; t += 4) {
            int sa = __shfl(myS, t + q, 64);
            half8 va = *(const half8*)(xl + (size_t)sa * 128 + c0);
            proc(va, (t + q) < cnt);
        }
    }

    // merge the 4 quadrant partials
    #pragma unroll
    for (int k = 0; k < 8; ++k) {
        acc[k] += __shfl_xor(acc[k], 16, 64);
        acc[k] += __shfl_xor(acc[k], 32, 64);
    }
    l += __shfl_xor(l, 16, 64);
    l += __shfl_xor(l, 32, 64);

    float inv = 1.0f / l;            // self loop guarantees l > 0
    float bv[8];
    *(float4*)&bv[0] = *(const float4*)(bias + c0);
    *(float4*)&bv[4] = *(const float4*)(bias + c0 + 4);
    float o[8];
    #pragma unroll
    for (int k = 0; k < 8; ++k) {
        o[k] = acc[k] * inv + bv[k];
        if (LAYER1) o[k] = fmaxf(o[k], 0.f);
    }
    if (lane < 16) {
        if (LAYER1) {
            __half2 hh2[4];
            #pragma unroll
            for (int k = 0; k < 4; ++k) hh2[k] = __floats2half2_rn(o[2 * k], o[2 * k + 1]);
            *(float4*)((_Float16*)outv + (size_t)node * 128 + c0) = *(float4*)&hh2[0];
        } else {
            float* out = (float*)outv;
            *(float4*)(out + (size_t)node * 128 + c0)     = *(float4*)&o[0];
            *(float4*)(out + (size_t)node * 128 + c0 + 4) = *(float4*)&o[4];
        }
    }
}

// ---------------- launch -----------------------------------------------------

extern "C" void kernel_launch(void* const* d_in, const int* in_sizes, int n_in,
                              void* d_out, int out_size, void* d_ws, size_t ws_size,
                              hipStream_t stream) {
    const float* x    = (const float*)d_in[0];
    const int*   ei   = (const int*)d_in[1];   // [2,E] int32
    const float* Wl1  = (const float*)d_in[2];
    const float* Wr1  = (const float*)d_in[3];
    const float* att1 = (const float*)d_in[4]; // [4,32] -> flat 128
    const float* b1   = (const float*)d_in[5];
    const float* Wl2  = (const float*)d_in[6];
    const float* Wr2  = (const float*)d_in[7];
    const float* att2 = (const float*)d_in[8]; // [1,128]
    const float* b2   = (const float*)d_in[9];

    int n  = in_sizes[0] / 128;
    int E  = in_sizes[1] / 2;
    int Et = E + n;                  // with self loops
    int npad = ((n + 1023) >> 10) << 10;   // counts/rowptr padding for int4 scan

    _Float16* xlh  = (_Float16*)d_ws;               // [n,128]
    _Float16* xrh2 = xlh + (size_t)n * 128;         // [n,128]
    _Float16* hh   = xrh2 + (size_t)n * 128;        // [n,128]
    _Float16* Wt1  = hh  + (size_t)n * 128;         // [256,128]
    _Float16* Wt2  = Wt1 + 256 * 128;               // [256,128]
    _Float16* attH = Wt2 + 256 * 128;               // [2][128]
    int* rowptr = (int*)(attH + 256);               // [npad + 16]
    int* cursor = rowptr + npad + 16;               // [npad]
    int* counts = cursor + npad;                    // [npad]
    int* srcs   = counts + npad;                    // [Et]

    const int* srcA = ei;
    const int* dstA = ei + E;

    int gemm_grid = (n + 63) / 64;
    int edge_grid = (n + 3) / 4;
    int GA = gemm_grid >> 1;         // gemm1 half in scan kernel
    int GB = gemm_grid - GA;         // gemm1 half in scatter kernel

    // 0: zero degree counters (graph-capturable stream memset)
    hipMemsetAsync(counts, 0, (size_t)npad * sizeof(int), stream);
    // 1: degree count (global atomics) || weight/att converts
    fused_pre<<<COUNTB + 257, 256, 0, stream>>>(
        dstA, counts, E, Et,
        Wl1, Wr1, Wl2, Wr2, att1, att2, Wt1, Wt2, attH);
    // 2: degree scan -> rowptr+cursor (1 block) || layer-1 GEMM first half
    fused_scan_gemm<<<1 + GA, 256, 0, stream>>>(
        counts, rowptr, cursor, x, Wt1, xlh, xrh2, n, Et);
    // 3: CSR scatter || layer-1 GEMM second half
    fused_scatter_gemm<<<SCATB + GB, 256, 0, stream>>>(
        srcA, dstA, cursor, srcs, E, Et, GA,
        x, Wt1, xlh, xrh2, n);
    // 4: layer-1 aggregation -> hh (fp16)
    edge_aggregate<true><<<edge_grid, 256, 0, stream>>>(
        xlh, xrh2, attH, b1, rowptr, srcs, hh, n);
    // 5: layer-2 GEMM
    gemm_l2<<<gemm_grid, 256, 0, stream>>>(hh, Wt2, xlh, xrh2, n);
    // 6: layer-2 aggregation -> d_out (fp32)
    edge_aggregate<false><<<edge_grid, 256, 0, stream>>>(
        xlh, xrh2, attH + 128, b2, rowptr, srcs, d_out, n);
}

// Round 3
// 282.022 us; speedup vs baseline: 1.0184x; 1.0184x over previous
//
#include <hip/hip_runtime.h>
#include <hip/hip_fp16.h>
#include <math.h>

// ---------------------------------------------------------------------------
// GATv2 x2 layers, N=50000, D=128, HID=128, heads 4 then 1, E=800000 (+ self loops)
//   1) CSR build by dst via two-level counting sort (LDS cursors, no global
//      atomics — R2 showed global-atomic scatter is 3x slower)
//   2) fp16 MFMA dual GEMM with LDS-staged B; layer-1 converts fp32 X in-register
//   3) layer-1: fused fine-sort + aggregation per 32-node bucket (sortD folded
//      into agg1; srcs/rowptr written for layer-2 on the side)
//   4) layer-2 aggregation: quadrant-per-edge, 4 gathers in flight, packed-fp16
//      leaky+dot, DPP logit reduction, exp-sum softmax
//   Overlap: [sortA | convert], [scan | gemm1a], [sortC | gemm1b].
// ---------------------------------------------------------------------------

#define NEG_SLOPE 0.2f
#define CHUNKS 64        // coarse chunks (sortA/sortC blocks)
#define NB 32            // nodes per bucket (dst>>5)
#define NBUCK_PAD 2048   // padded bucket count (multiple of 256)
#define DCAP 1024        // per-bucket edge capacity (mean ~544)

typedef _Float16 half8 __attribute__((ext_vector_type(8)));
typedef _Float16 half2v __attribute__((ext_vector_type(2)));
typedef float floatx4 __attribute__((ext_vector_type(4)));

#if defined(__has_builtin)
#if __has_builtin(__builtin_amdgcn_fdot2)
#define HAVE_FDOT2 1
#endif
#endif

// DPP cross-lane add helpers (VALU pipe, no LDS traffic)
template <int CTRL>
__device__ __forceinline__ float dppmov(float x) {
    int xi = __builtin_bit_cast(int, x);
    int r  = __builtin_amdgcn_update_dpp(0, xi, CTRL, 0xF, 0xF, true);
    return __builtin_bit_cast(float, r);
}
#define DPP_XOR1  0xB1   // quad_perm [1,0,3,2]
#define DPP_XOR2  0x4E   // quad_perm [2,3,0,1]
#define DPP_HMIRR 0x141  // row_half_mirror (lane^7 within 8)
#define DPP_MIRR  0x140  // row_mirror      (lane^15 within 16)

// ---------------- device bodies ----------------------------------------------

// sortA: coarse histogram per chunk over 2048 buckets (dst>>5), bucket-major out
__device__ __forceinline__ void sortA_body(int c, const int* __restrict__ dstA,
                                           int* __restrict__ hist_mat,
                                           int E, int Et, int csz) {
    __shared__ int hist[NBUCK_PAD];
    int tid = threadIdx.x;
    for (int k = tid; k < NBUCK_PAD; k += 256) hist[k] = 0;
    __syncthreads();
    int start = c * csz, stop = min(Et, start + csz);
    for (int e = start + tid; e < stop; e += 256) {
        int d = (e < E) ? dstA[e] : (e - E);
        atomicAdd(&hist[d >> 5], 1);
    }
    __syncthreads();
    for (int k = tid; k < NBUCK_PAD; k += 256)
        hist_mat[k * CHUNKS + c] = hist[k];   // zeros for padded buckets
}

// convert: Wt[c][k] fp16 transposed dual for both layers + att1/att2 -> fp16
__device__ __forceinline__ void convert_body(int t,
        const float* __restrict__ Wl1, const float* __restrict__ Wr1,
        const float* __restrict__ Wl2, const float* __restrict__ Wr2,
        const float* __restrict__ att1, const float* __restrict__ att2,
        _Float16* __restrict__ Wt1, _Float16* __restrict__ Wt2,
        _Float16* __restrict__ attH) {
    if (t < 65536) {
        int layer = t >> 15;
        int id = t & 32767;
        int c = id >> 7, k = id & 127;
        const float* Wl = layer ? Wl2 : Wl1;
        const float* Wr = layer ? Wr2 : Wr1;
        _Float16* Wt = layer ? Wt2 : Wt1;
        float v = (c < 128) ? Wl[(size_t)k * 128 + c] : Wr[(size_t)k * 128 + (c - 128)];
        Wt[(size_t)c * 128 + k] = (_Float16)v;
    } else {
        int id = t - 65536;          // 0..255
        if (id < 256) {
            float v = (id < 128) ? att1[id] : att2[id - 128];
            attH[id] = (_Float16)v;
        }
    }
}

// scan: exclusive scan of 2048x64 hist (flat f = bucket*64 + chunk), one block.
// Thread t owns buckets 8t..8t+7 = 512 contiguous ints (128 int4).
__device__ __forceinline__ void scan_body(const int* __restrict__ hist_mat,
                                          int* __restrict__ offs_flat) {
    __shared__ int wsum[4];
    int t = threadIdx.x;          // 0..255
    int lane = t & 63, w = t >> 6;
    const int4* hp = (const int4*)hist_mat + (size_t)t * 128;
    int local = 0;
    #pragma unroll 8
    for (int j = 0; j < 128; ++j) {
        int4 v = hp[j];
        local += v.x + v.y + v.z + v.w;
    }
    int x = local;
    #pragma unroll
    for (int off = 1; off < 64; off <<= 1) {
        int y = __shfl_up(x, off, 64);
        if (lane >= off) x += y;
    }
    if (lane == 63) wsum[w] = x;
    __syncthreads();
    int woff = 0;
    for (int i = 0; i < w; ++i) woff += wsum[i];
    int run = woff + x - local;   // exclusive prefix of this thread's first value
    int4* op = (int4*)offs_flat + (size_t)t * 128;
    #pragma unroll 8
    for (int j = 0; j < 128; ++j) {
        int4 v = hp[j];
        int4 o;
        o.x = run;
        o.y = run + v.x;
        o.z = o.y + v.y;
        o.w = o.z + v.z;
        run = o.w + v.w;
        op[j] = o;
    }
}

// sortC: coarse scatter into bucket regions; packed = (dst&31)<<16 | src
__device__ __forceinline__ void sortC_body(int c, const int* __restrict__ srcA,
        const int* __restrict__ dstA, const int* __restrict__ offs_flat,
        int* __restrict__ packed, int E, int Et, int csz) {
    __shared__ int pos[NBUCK_PAD];
    int tid = threadIdx.x;
    for (int k = tid; k < NBUCK_PAD; k += 256)
        pos[k] = offs_flat[k * CHUNKS + c];
    __syncthreads();
    int start = c * csz, stop = min(Et, start + csz);
    for (int e = start + tid; e < stop; e += 256) {
        int s, d;
        if (e < E) { s = srcA[e]; d = dstA[e]; } else { s = e - E; d = s; }
        int p = atomicAdd(&pos[d >> 5], 1);
        packed[p] = ((d & 31) << 16) | s;
    }
}

// gemm: C[n x 256] = A[n x 128] @ W[128 x 256]; cols 0-127 -> outL (fp16),
// 128-255 -> outR (fp16). B (Wt, transposed) staged in LDS.
#define BPAD 136   // LDS row length in halves (128 + 8 pad)

template <bool AF32>
__device__ __forceinline__ void gemm_body(int bid, const void* __restrict__ Av,
        const _Float16* __restrict__ Bt, _Float16* __restrict__ outL,
        _Float16* __restrict__ outR, int n) {
    __shared__ _Float16 sB[256 * BPAD];
    int tid = threadIdx.x;
    {
        int c0 = (tid & 15) * 8;
        int r0 = tid >> 4;
        #pragma unroll
        for (int i = 0; i < 16; ++i) {
            int r = r0 + i * 16;
            *(half8*)(sB + r * BPAD + c0) = *(const half8*)(Bt + (size_t)r * 128 + c0);
        }
    }
    int wave = tid >> 6;
    int lane = tid & 63;
    int ln = lane & 15;
    int q  = lane >> 4;
    int row0 = bid * 64 + wave * 16;

    int arow = row0 + ln;
    if (arow >= n) arow = n - 1;             // clamp; stores guarded below
    half8 a0, a1, a2, a3;
    if (AF32) {
        const float* ap = (const float*)Av + (size_t)arow * 128 + q * 8;
        #pragma unroll
        for (int g = 0; g < 4; ++g) {
            float4 f0 = *(const float4*)(ap + g * 32);
            float4 f1 = *(const float4*)(ap + g * 32 + 4);
            half8 h;
            h[0] = (_Float16)f0.x; h[1] = (_Float16)f0.y;
            h[2] = (_Float16)f0.z; h[3] = (_Float16)f0.w;
            h[4] = (_Float16)f1.x; h[5] = (_Float16)f1.y;
            h[6] = (_Float16)f1.z; h[7] = (_Float16)f1.w;
            if (g == 0) a0 = h; else if (g == 1) a1 = h;
            else if (g == 2) a2 = h; else a3 = h;
        }
    } else {
        const _Float16* ap = (const _Float16*)Av + (size_t)arow * 128 + q * 8;
        a0 = *(const half8*)(ap);
        a1 = *(const half8*)(ap + 32);
        a2 = *(const half8*)(ap + 64);
        a3 = *(const half8*)(ap + 96);
    }

    __syncthreads();

    floatx4 acc[16];
    #pragma unroll
    for (int ct = 0; ct < 16; ++ct) {
        const _Float16* bp = sB + (ct * 16 + ln) * BPAD + q * 8;
        half8 b0 = *(const half8*)(bp);
        half8 b1 = *(const half8*)(bp + 32);
        half8 b2 = *(const half8*)(bp + 64);
        half8 b3 = *(const half8*)(bp + 96);
        floatx4 c = {0.f, 0.f, 0.f, 0.f};
        c = __builtin_amdgcn_mfma_f32_16x16x32_f16(a0, b0, c, 0, 0, 0);
        c = __builtin_amdgcn_mfma_f32_16x16x32_f16(a1, b1, c, 0, 0, 0);
        c = __builtin_amdgcn_mfma_f32_16x16x32_f16(a2, b2, c, 0, 0, 0);
        c = __builtin_amdgcn_mfma_f32_16x16x32_f16(a3, b3, c, 0, 0, 0);
        acc[ct] = c;
    }

    #pragma unroll
    for (int ct = 0; ct < 16; ++ct) {
        int col = ct * 16 + ln;
        #pragma unroll
        for (int r = 0; r < 4; ++r) {
            int grow = row0 + q * 4 + r;
            if (grow < n) {
                _Float16 v = (_Float16)acc[ct][r];
                if (ct < 8) outL[(size_t)grow * 128 + col] = v;
                else        outR[(size_t)grow * 128 + (col - 128)] = v;
            }
        }
    }
}

// ---------------- fused kernels ----------------------------------------------

// fused_pre: blocks 0..CHUNKS-1 sortA; blocks CHUNKS.. convert weights/att
__global__ __launch_bounds__(256)
void fused_pre(const int* __restrict__ dstA, int* __restrict__ hist_mat,
               int E, int Et, int csz,
               const float* __restrict__ Wl1, const float* __restrict__ Wr1,
               const float* __restrict__ Wl2, const float* __restrict__ Wr2,
               const float* __restrict__ att1, const float* __restrict__ att2,
               _Float16* __restrict__ Wt1, _Float16* __restrict__ Wt2,
               _Float16* __restrict__ attH) {
    if (blockIdx.x < CHUNKS) {
        sortA_body(blockIdx.x, dstA, hist_mat, E, Et, csz);
    } else {
        int t = (blockIdx.x - CHUNKS) * 256 + threadIdx.x;
        convert_body(t, Wl1, Wr1, Wl2, Wr2, att1, att2, Wt1, Wt2, attH);
    }
}

// fused_scan_gemm: block 0 = hist scan; blocks 1.. = first half of layer-1 GEMM
__global__ __launch_bounds__(256)
void fused_scan_gemm(const int* __restrict__ hist_mat, int* __restrict__ offs_flat,
                     const float* __restrict__ X, const _Float16* __restrict__ Wt1,
                     _Float16* __restrict__ outL, _Float16* __restrict__ outR, int n) {
    if (blockIdx.x == 0) {
        scan_body(hist_mat, offs_flat);
    } else {
        gemm_body<true>(blockIdx.x - 1, X, Wt1, outL, outR, n);
    }
}

// fused_mid: blocks 0..CHUNKS-1 sortC; blocks CHUNKS.. second half of gemm1
__global__ __launch_bounds__(256)
void fused_mid(const int* __restrict__ srcA, const int* __restrict__ dstA,
               const int* __restrict__ offs_flat, int* __restrict__ packed,
               int E, int Et, int csz, int gemm_base,
               const float* __restrict__ X, const _Float16* __restrict__ Wt1,
               _Float16* __restrict__ outL, _Float16* __restrict__ outR, int n) {
    if (blockIdx.x < CHUNKS) {
        sortC_body(blockIdx.x, srcA, dstA, offs_flat, packed, E, Et, csz);
    } else {
        gemm_body<true>(blockIdx.x - CHUNKS + gemm_base, X, Wt1, outL, outR, n);
    }
}

// layer-2 GEMM standalone
__global__ __launch_bounds__(256)
void gemm_l2(const _Float16* __restrict__ A, const _Float16* __restrict__ Bt,
             _Float16* __restrict__ outL, _Float16* __restrict__ outR, int n) {
    gemm_body<false>(blockIdx.x, A, Bt, outL, outR, n);
}

// ---------------- sort_agg: fused fine-sort + layer-1 aggregation ------------
// Block = one 32-node bucket. Phase 1: LDS fine sort (hist/scan/scatter) of the
// bucket's packed edges; writes rowptr+srcs for layer-2 on the side. Phase 2:
// each of 4 waves aggregates 8 nodes, reading srcs from LDS (16-bit).
// Quadrant-per-edge proc identical to edge_aggregate (layer-1 DPP variant).

__global__ __launch_bounds__(256)
void sort_agg(const int* __restrict__ offs_flat, const int* __restrict__ packed,
              int* __restrict__ rowptr, int* __restrict__ srcs,
              const _Float16* __restrict__ xl, const _Float16* __restrict__ xr,
              const _Float16* __restrict__ attH, const float* __restrict__ bias,
              _Float16* __restrict__ out, int n, int Et) {
    __shared__ int stage[DCAP];
    __shared__ unsigned short s16[DCAP];
    __shared__ int hist[NB];
    __shared__ int curv[NB];
    __shared__ int rp_l[NB + 1];

    int tid = threadIdx.x, b = blockIdx.x;
    int base = offs_flat[b * CHUNKS];
    int end  = offs_flat[(b + 1) * CHUNKS];  // padded buckets carry Et
    int m = min(end - base, DCAP);
    int node0 = b * NB;

    if (tid < NB) hist[tid] = 0;
    for (int i = tid; i < m; i += 256) stage[i] = packed[base + i];
    __syncthreads();
    for (int i = tid; i < m; i += 256) atomicAdd(&hist[stage[i] >> 16], 1);
    __syncthreads();
    if (tid < 64) {
        int lane = tid;
        int v = (lane < NB) ? hist[lane] : 0;
        int x = v;
        #pragma unroll
        for (int off = 1; off < 64; off <<= 1) {
            int y = __shfl_up(x, off, 64);
            if (lane >= off) x += y;
        }
        if (lane < NB) { rp_l[lane] = x - v; curv[lane] = x - v; }
        if (lane == NB - 1) rp_l[NB] = x;
    }
    __syncthreads();
    for (int i = tid; i < m; i += 256) {
        int p = stage[i];
        int pos = atomicAdd(&curv[p >> 16], 1);
        s16[pos] = (unsigned short)(p & 0xFFFF);
    }
    __syncthreads();

    // CSR writeback for layer-2 (fire-and-forget stores)
    if (tid < NB && node0 + tid < n) rowptr[node0 + tid] = base + rp_l[tid];
    if (b == 0 && tid == 0) rowptr[n] = Et;
    for (int i = tid; i < m; i += 256) srcs[base + i] = (int)s16[i];

    // ---- aggregation: 8 nodes per wave, edges from LDS ----
    int w = tid >> 6, lane = tid & 63;
    int ln = lane & 15, q = lane >> 4, c0 = ln * 8;
    half8 ahh = *(const half8*)(attH + c0);
    float bv[8];
    *(float4*)&bv[0] = *(const float4*)(bias + c0);
    *(float4*)&bv[4] = *(const float4*)(bias + c0 + 4);

    for (int i = 0; i < NB / 4; ++i) {
        int j = w * (NB / 4) + i;
        int node = node0 + j;
        if (node >= n) break;               // uniform per wave
        half8 xrh = *(const half8*)(xr + (size_t)node * 128 + c0);
        float acc[8] = {0.f, 0.f, 0.f, 0.f, 0.f, 0.f, 0.f, 0.f};
        float l = 0.f;

        auto proc = [&](half8 vh, bool valid) {
            half8 e  = vh + xrh;
            half8 es = e * (_Float16)NEG_SLOPE;
            half8 lr = __builtin_elementwise_max(e, es);
            float p = 0.f;
            #pragma unroll
            for (int k = 0; k < 4; ++k) {
                half2v ee = { lr[2 * k], lr[2 * k + 1] };
                half2v aa = { ahh[2 * k], ahh[2 * k + 1] };
#ifdef HAVE_FDOT2
                p = __builtin_amdgcn_fdot2(ee, aa, p, false);
#else
                p = fmaf((float)ee[0], (float)aa[0], p);
                p = fmaf((float)ee[1], (float)aa[1], p);
#endif
            }
            p += dppmov<DPP_XOR1>(p);
            p += dppmov<DPP_XOR2>(p);       // layer-1: per-head (32ch = 4 lanes)
            float pe = __expf(p);
            if (!valid) pe = 0.f;
            l += pe;
            #pragma unroll
            for (int k = 0; k < 8; ++k) acc[k] = fmaf(pe, (float)vh[k], acc[k]);
        };

        int jb = rp_l[j], je = rp_l[j + 1];
        for (int be = jb; be < je; be += 64) {
            int idx = be + lane;
            int myS = (idx < je) ? (int)s16[idx] : 0;
            int cnt = min(64, je - be);
            int t = 0;
            for (; t + 16 <= cnt; t += 16) {
                int s0 = __shfl(myS, t + q, 64);
                int s1 = __shfl(myS, t + 4 + q, 64);
                int s2 = __shfl(myS, t + 8 + q, 64);
                int s3 = __shfl(myS, t + 12 + q, 64);
                half8 v0 = *(const half8*)(xl + (size_t)s0 * 128 + c0);
                half8 v1 = *(const half8*)(xl + (size_t)s1 * 128 + c0);
                half8 v2 = *(const half8*)(xl + (size_t)s2 * 128 + c0);
                half8 v3 = *(const half8*)(xl + (size_t)s3 * 128 + c0);
                proc(v0, true); proc(v1, true); proc(v2, true); proc(v3, true);
            }
            for (; t < cnt; t += 4) {
                int sa = __shfl(myS, t + q, 64);
                half8 va = *(const half8*)(xl + (size_t)sa * 128 + c0);
                proc(va, (t + q) < cnt);
            }
        }

        #pragma unroll
        for (int k = 0; k < 8; ++k) {
            acc[k] += __shfl_xor(acc[k], 16, 64);
            acc[k] += __shfl_xor(acc[k], 32, 64);
        }
        l += __shfl_xor(l, 16, 64);
        l += __shfl_xor(l, 32, 64);

        float inv = 1.0f / l;                // self loop guarantees l > 0
        float o[8];
        #pragma unroll
        for (int k = 0; k < 8; ++k)
            o[k] = fmaxf(acc[k] * inv + bv[k], 0.f);   // + ReLU
        if (lane < 16) {
            __half2 hh2[4];
            #pragma unroll
            for (int k = 0; k < 4; ++k) hh2[k] = __floats2half2_rn(o[2 * k], o[2 * k + 1]);
            *(float4*)(out + (size_t)node * 128 + c0) = *(float4*)&hh2[0];
        }
    }
}

// ---------------- edge aggregation (layer 2): wave-per-node ------------------

template <bool LAYER1>
__global__ __launch_bounds__(256)
void edge_aggregate(const _Float16* __restrict__ xl, const _Float16* __restrict__ xr,
                    const _Float16* __restrict__ attH, const float* __restrict__ bias,
                    const int* __restrict__ rowptr, const int* __restrict__ srcs,
                    void* __restrict__ outv, int n) {
    int node = blockIdx.x * (blockDim.x >> 6) + (threadIdx.x >> 6);
    int lane = threadIdx.x & 63;
    if (node >= n) return;
    int ln = lane & 15;
    int q  = lane >> 4;
    int c0 = ln * 8;

    half8 xrh = *(const half8*)(xr + (size_t)node * 128 + c0);
    half8 ahh = *(const half8*)(attH + c0);

    float acc[8] = {0.f, 0.f, 0.f, 0.f, 0.f, 0.f, 0.f, 0.f};
    float l = 0.f;

    auto proc = [&](half8 vh, bool valid) {
        half8 e  = vh + xrh;
        half8 es = e * (_Float16)NEG_SLOPE;
        half8 lr = __builtin_elementwise_max(e, es);
        float p = 0.f;
        #pragma unroll
        for (int k = 0; k < 4; ++k) {
            half2v ee = { lr[2 * k], lr[2 * k + 1] };
            half2v aa = { ahh[2 * k], ahh[2 * k + 1] };
#ifdef HAVE_FDOT2
            p = __builtin_amdgcn_fdot2(ee, aa, p, false);
#else
            p = fmaf((float)ee[0], (float)aa[0], p);
            p = fmaf((float)ee[1], (float)aa[1], p);
#endif
        }
        p += dppmov<DPP_XOR1>(p);
        p += dppmov<DPP_XOR2>(p);
        if (!LAYER1) { p += dppmov<DPP_HMIRR>(p); p += dppmov<DPP_MIRR>(p); }
        float pe = __expf(p);
        if (!valid) pe = 0.f;
        l += pe;
        #pragma unroll
        for (int k = 0; k < 8; ++k) acc[k] = fmaf(pe, (float)vh[k], acc[k]);
    };

    int jb = rowptr[node], je = rowptr[node + 1];
    for (int base = jb; base < je; base += 64) {
        int idx = base + lane;
        int myS = (idx < je) ? srcs[idx] : 0;
        int cnt = min(64, je - base);
        int t = 0;
        for (; t + 16 <= cnt; t += 16) {
            int s0 = __shfl(myS, t + q, 64);
            int s1 = __shfl(myS, t + 4 + q, 64);
            int s2 = __shfl(myS, t + 8 + q, 64);
            int s3 = __shfl(myS, t + 12 + q, 64);
            half8 v0 = *(const half8*)(xl + (size_t)s0 * 128 + c0);
            half8 v1 = *(const half8*)(xl + (size_t)s1 * 128 + c0);
            half8 v2 = *(const half8*)(xl + (size_t)s2 * 128 + c0);
            half8 v3 = *(const half8*)(xl + (size_t)s3 * 128 + c0);
            proc(v0, true); proc(v1, true); proc(v2, true); proc(v3, true);
        }
        for (; t < cnt; t += 4) {
            int sa = __shfl(myS, t + q, 64);
            half8 va = *(const half8*)(xl + (size_t)sa * 128 + c0);
            proc(va, (t + q) < cnt);
        }
    }

    #pragma unroll
    for (int k = 0; k < 8; ++k) {
        acc[k] += __shfl_xor(acc[k], 16, 64);
        acc[k] += __shfl_xor(acc[k], 32, 64);
    }
    l += __shfl_xor(l, 16, 64);
    l += __shfl_xor(l, 32, 64);

    float inv = 1.0f / l;            // self loop guarantees l > 0
    float bv[8];
    *(float4*)&bv[0] = *(const float4*)(bias + c0);
    *(float4*)&bv[4] = *(const float4*)(bias + c0 + 4);
    float o[8];
    #pragma unroll
    for (int k = 0; k < 8; ++k) {
        o[k] = acc[k] * inv + bv[k];
        if (LAYER1) o[k] = fmaxf(o[k], 0.f);
    }
    if (lane < 16) {
        if (LAYER1) {
            __half2 hh2[4];
            #pragma unroll
            for (int k = 0; k < 4; ++k) hh2[k] = __floats2half2_rn(o[2 * k], o[2 * k + 1]);
            *(float4*)((_Float16*)outv + (size_t)node * 128 + c0) = *(float4*)&hh2[0];
        } else {
            float* out = (float*)outv;
            *(float4*)(out + (size_t)node * 128 + c0)     = *(float4*)&o[0];
            *(float4*)(out + (size_t)node * 128 + c0 + 4) = *(float4*)&o[4];
        }
    }
}

// ---------------- launch -----------------------------------------------------

extern "C" void kernel_launch(void* const* d_in, const int* in_sizes, int n_in,
                              void* d_out, int out_size, void* d_ws, size_t ws_size,
                              hipStream_t stream) {
    const float* x    = (const float*)d_in[0];
    const int*   ei   = (const int*)d_in[1];   // [2,E] int32
    const float* Wl1  = (const float*)d_in[2];
    const float* Wr1  = (const float*)d_in[3];
    const float* att1 = (const float*)d_in[4]; // [4,32] -> flat 128
    const float* b1   = (const float*)d_in[5];
    const float* Wl2  = (const float*)d_in[6];
    const float* Wr2  = (const float*)d_in[7];
    const float* att2 = (const float*)d_in[8]; // [1,128]
    const float* b2   = (const float*)d_in[9];

    int n  = in_sizes[0] / 128;
    int E  = in_sizes[1] / 2;
    int Et = E + n;                  // with self loops

    _Float16* xlh  = (_Float16*)d_ws;               // [n,128]
    _Float16* xrh2 = xlh + (size_t)n * 128;         // [n,128]
    _Float16* hh   = xrh2 + (size_t)n * 128;        // [n,128]
    _Float16* Wt1  = hh  + (size_t)n * 128;         // [256,128]
    _Float16* Wt2  = Wt1 + 256 * 128;               // [256,128]
    _Float16* attH = Wt2 + 256 * 128;               // [2][128]
    int* rowptr   = (int*)(attH + 256);             // [n+1] padded
    int* packed   = rowptr + ((n + 16) & ~3);       // [Et]
    int* srcs     = packed + Et;                    // [Et]
    int* hist_mat = srcs + Et;                      // [2048*64] bucket-major
    int* offs_flat= hist_mat + NBUCK_PAD * CHUNKS;  // [2048*64]

    const int* srcA = ei;
    const int* dstA = ei + E;

    int csz   = (Et + CHUNKS - 1) / CHUNKS;
    int nbuck = (n + NB - 1) / NB;
    int gemm_grid = (n + 63) / 64;
    int edge_grid = (n + 3) / 4;
    int GA = gemm_grid >> 1;         // gemm1 half in scan kernel
    int GB = gemm_grid - GA;         // gemm1 half in sortC kernel

    // 1: sortA (coarse hist, bucket-major) || weight/att converts
    fused_pre<<<CHUNKS + 257, 256, 0, stream>>>(
        dstA, hist_mat, E, Et, csz,
        Wl1, Wr1, Wl2, Wr2, att1, att2, Wt1, Wt2, attH);
    // 2: hist scan (1 block) || layer-1 GEMM first half
    fused_scan_gemm<<<1 + GA, 256, 0, stream>>>(
        hist_mat, offs_flat, x, Wt1, xlh, xrh2, n);
    // 3: sortC (coarse scatter) || layer-1 GEMM second half
    fused_mid<<<CHUNKS + GB, 256, 0, stream>>>(
        srcA, dstA, offs_flat, packed, E, Et, csz, GA,
        x, Wt1, xlh, xrh2, n);
    // 4: fused fine-sort + layer-1 aggregation -> hh, rowptr, srcs
    sort_agg<<<nbuck, 256, 0, stream>>>(
        offs_flat, packed, rowptr, srcs, xlh, xrh2, attH, b1, hh, n, Et);
    // 5: layer-2 GEMM
    gemm_l2<<<gemm_grid, 256, 0, stream>>>(hh, Wt2, xlh, xrh2, n);
    // 6: layer-2 aggregation -> d_out (fp32)
    edge_aggregate<false><<<edge_grid, 256, 0, stream>>>(
        xlh, xrh2, attH + 128, b2, rowptr, srcs, d_out, n);
}

// Round 4
// 224.188 us; speedup vs baseline: 1.2811x; 1.2580x over previous
//
#include <hip/hip_runtime.h>
#include <hip/hip_fp16.h>
#include <math.h>

// ---------------------------------------------------------------------------
// GATv2 x2 layers, N=50000, D=128, HID=128, heads 4 then 1, E=800000 (+ self loops)
//   1) CSR build by dst via two-level counting sort (LDS cursors; R2 showed
//      global-atomic scatter is 3x slower, R3 showed finer buckets blow up the
//      serial scan). 256-node buckets, 128 chunks, 32K-entry scan.
//   2) fp16 MFMA dual GEMM with LDS-staged B; layer-1 converts fp32 X in-register
//   3) edge aggregation: quadrant-per-edge, 4 gathers in flight, packed-fp16
//      leaky+dot, DPP logit reduction, exp-sum softmax (no running max)
//   Overlap: [sortA | convert], [scan | gemm1a], [sortC | gemm1b],
//            [sortD | gemm1c]  <- new: all four sort stages are now covered.
//   fused_sortD_gemm uses a dynamic-LDS union (69632B) so sortD (50KB) and
//   gemm (68KB) don't sum to 118KB and halve occupancy.
// ---------------------------------------------------------------------------

#define NEG_SLOPE 0.2f
#define CHUNKS 128
#define DCAP 8192   // per-bucket capacity in kernel D (expected max ~4600)

typedef _Float16 half8 __attribute__((ext_vector_type(8)));
typedef _Float16 half2v __attribute__((ext_vector_type(2)));
typedef float floatx4 __attribute__((ext_vector_type(4)));

#if defined(__has_builtin)
#if __has_builtin(__builtin_amdgcn_fdot2)
#define HAVE_FDOT2 1
#endif
#endif

// DPP cross-lane add helpers (VALU pipe, no LDS traffic)
template <int CTRL>
__device__ __forceinline__ float dppmov(float x) {
    int xi = __builtin_bit_cast(int, x);
    int r  = __builtin_amdgcn_update_dpp(0, xi, CTRL, 0xF, 0xF, true);
    return __builtin_bit_cast(float, r);
}
#define DPP_XOR1  0xB1   // quad_perm [1,0,3,2]
#define DPP_XOR2  0x4E   // quad_perm [2,3,0,1]
#define DPP_HMIRR 0x141  // row_half_mirror (lane^7 within 8)
#define DPP_MIRR  0x140  // row_mirror      (lane^15 within 16)

// ---------------- device bodies ----------------------------------------------

// sortA: coarse histogram per chunk (dst>>8), written BUCKET-MAJOR so the scan
// can read each bucket's 128 chunk-counts contiguously (int4).
__device__ __forceinline__ void sortA_body(int c, const int* __restrict__ dstA,
                                           int* __restrict__ hist_mat,
                                           int E, int Et, int csz) {
    __shared__ int hist[256];
    int tid = threadIdx.x;
    hist[tid] = 0;
    __syncthreads();
    int start = c * csz, stop = min(Et, start + csz);
    for (int e = start + tid; e < stop; e += 256) {
        int d = (e < E) ? dstA[e] : (e - E);
        atomicAdd(&hist[d >> 8], 1);
    }
    __syncthreads();
    hist_mat[tid * CHUNKS + c] = hist[tid];   // bucket-major
}

// convert: Wt[c][k] fp16 transposed dual for both layers + att1/att2 -> fp16
__device__ __forceinline__ void convert_body(int t,
        const float* __restrict__ Wl1, const float* __restrict__ Wr1,
        const float* __restrict__ Wl2, const float* __restrict__ Wr2,
        const float* __restrict__ att1, const float* __restrict__ att2,
        _Float16* __restrict__ Wt1, _Float16* __restrict__ Wt2,
        _Float16* __restrict__ attH) {
    if (t < 65536) {
        int layer = t >> 15;
        int id = t & 32767;
        int c = id >> 7, k = id & 127;
        const float* Wl = layer ? Wl2 : Wl1;
        const float* Wr = layer ? Wr2 : Wr1;
        _Float16* Wt = layer ? Wt2 : Wt1;
        float v = (c < 128) ? Wl[(size_t)k * 128 + c] : Wr[(size_t)k * 128 + (c - 128)];
        Wt[(size_t)c * 128 + k] = (_Float16)v;
    } else {
        int id = t - 65536;          // 0..255
        if (id < 256) {
            float v = (id < 128) ? att1[id] : att2[id - 128];
            attH[id] = (_Float16)v;
        }
    }
}

// scan256: exclusive scan of 32768 hist values in flat order f = bucket*128+chunk.
// Thread t owns bucket t (128 contiguous ints, bucket-major layout). One block.
__device__ __forceinline__ void scan256_body(const int* __restrict__ hist_mat,
                                             int* __restrict__ offs_flat) {
    __shared__ int wsum[4];
    int t = threadIdx.x;          // 0..255
    int lane = t & 63, w = t >> 6;
    const int4* hp = (const int4*)hist_mat + t * 32;   // 128 ints = 32 int4
    int local = 0;
    #pragma unroll 8
    for (int j = 0; j < 32; ++j) {
        int4 v = hp[j];
        local += v.x + v.y + v.z + v.w;
    }
    int x = local;
    #pragma unroll
    for (int off = 1; off < 64; off <<= 1) {
        int y = __shfl_up(x, off, 64);
        if (lane >= off) x += y;
    }
    if (lane == 63) wsum[w] = x;
    __syncthreads();
    int woff = 0;
    for (int i = 0; i < w; ++i) woff += wsum[i];
    int run = woff + x - local;   // exclusive prefix of this bucket's first chunk
    int4* op = (int4*)offs_flat + t * 32;
    #pragma unroll 8
    for (int j = 0; j < 32; ++j) {
        int4 v = hp[j];
        int4 o;
        o.x = run;
        o.y = run + v.x;
        o.z = o.y + v.y;
        o.w = o.z + v.z;
        run = o.w + v.w;
        op[j] = o;
    }
}

// sortC: coarse scatter into bucket regions; packed = (dst&255)<<16 | src
__device__ __forceinline__ void sortC_body(int c, const int* __restrict__ srcA,
        const int* __restrict__ dstA, const int* __restrict__ offs_flat,
        int* __restrict__ packed, int E, int Et, int csz) {
    __shared__ int pos[256];
    int tid = threadIdx.x;
    pos[tid] = offs_flat[tid * CHUNKS + c];
    __syncthreads();
    int start = c * csz, stop = min(Et, start + csz);
    for (int e = start + tid; e < stop; e += 256) {
        int s, d;
        if (e < E) { s = srcA[e]; d = dstA[e]; } else { s = e - E; d = s; }
        int p = atomicAdd(&pos[d >> 8], 1);
        packed[p] = ((d & 255) << 16) | s;
    }
}

// sortD: per-bucket fine sort in LDS -> rowptr + contiguous srcs.
// LDS carved from smem: stage int[DCAP] | s16 u16[DCAP] | hist[256] | curv[256]
// | wsumD[4]  (total ~50.2 KB)
__device__ __forceinline__ void sortD_body(int b, const int* __restrict__ offs_flat,
        const int* __restrict__ packed, int* __restrict__ rowptr,
        int* __restrict__ srcs, int n, int Et, int nbuck, char* smem) {
    int* stage = (int*)smem;                                   // [DCAP]
    unsigned short* s16 = (unsigned short*)(smem + DCAP * 4);  // [DCAP]
    int* hist  = (int*)(smem + DCAP * 6);                      // [256]
    int* curv  = hist + 256;                                   // [256]
    int* wsumD = curv + 256;                                   // [4]
    int tid = threadIdx.x;
    int base = offs_flat[b * CHUNKS];
    int end  = (b == nbuck - 1) ? Et : offs_flat[(b + 1) * CHUNKS];
    int m = min(end - base, DCAP);

    hist[tid] = 0;
    for (int i = tid; i < m; i += 256) stage[i] = packed[base + i];
    __syncthreads();
    for (int i = tid; i < m; i += 256) atomicAdd(&hist[stage[i] >> 16], 1);
    __syncthreads();
    {
        int v = hist[tid];
        int lane = tid & 63, w = tid >> 6;
        int x = v;
        #pragma unroll
        for (int off = 1; off < 64; off <<= 1) {
            int y = __shfl_up(x, off, 64);
            if (lane >= off) x += y;
        }
        if (lane == 63) wsumD[w] = x;
        __syncthreads();
        int woff = 0;
        for (int i = 0; i < w; ++i) woff += wsumD[i];
        int excl = woff + x - v;
        curv[tid] = excl;
        int node0 = b << 8;
        if (node0 + tid < n) rowptr[node0 + tid] = base + excl;
        if (b == 0 && tid == 0) rowptr[n] = Et;
    }
    __syncthreads();
    for (int i = tid; i < m; i += 256) {
        int p = stage[i];
        int pos = atomicAdd(&curv[p >> 16], 1);
        s16[pos] = (unsigned short)(p & 0xFFFF);
    }
    __syncthreads();
    for (int i = tid; i < m; i += 256) srcs[base + i] = (int)s16[i];
}

// gemm: C[n x 256] = A[n x 128] @ W[128 x 256]; cols 0-127 -> outL (fp16),
// 128-255 -> outR (fp16). B (Wt, transposed) staged in caller-provided LDS.
#define BPAD 136   // LDS row length in halves (128 + 8 pad)
#define GEMM_LDS_BYTES (256 * BPAD * 2)   // 69632

template <bool AF32>
__device__ __forceinline__ void gemm_body(int bid, const void* __restrict__ Av,
        const _Float16* __restrict__ Bt, _Float16* __restrict__ outL,
        _Float16* __restrict__ outR, int n, _Float16* sB) {
    int tid = threadIdx.x;
    {
        int c0 = (tid & 15) * 8;
        int r0 = tid >> 4;
        #pragma unroll
        for (int i = 0; i < 16; ++i) {
            int r = r0 + i * 16;
            *(half8*)(sB + r * BPAD + c0) = *(const half8*)(Bt + (size_t)r * 128 + c0);
        }
    }
    int wave = tid >> 6;
    int lane = tid & 63;
    int ln = lane & 15;
    int q  = lane >> 4;
    int row0 = bid * 64 + wave * 16;

    int arow = row0 + ln;
    if (arow >= n) arow = n - 1;             // clamp; stores guarded below
    half8 a0, a1, a2, a3;
    if (AF32) {
        const float* ap = (const float*)Av + (size_t)arow * 128 + q * 8;
        #pragma unroll
        for (int g = 0; g < 4; ++g) {
            float4 f0 = *(const float4*)(ap + g * 32);
            float4 f1 = *(const float4*)(ap + g * 32 + 4);
            half8 h;
            h[0] = (_Float16)f0.x; h[1] = (_Float16)f0.y;
            h[2] = (_Float16)f0.z; h[3] = (_Float16)f0.w;
            h[4] = (_Float16)f1.x; h[5] = (_Float16)f1.y;
            h[6] = (_Float16)f1.z; h[7] = (_Float16)f1.w;
            if (g == 0) a0 = h; else if (g == 1) a1 = h;
            else if (g == 2) a2 = h; else a3 = h;
        }
    } else {
        const _Float16* ap = (const _Float16*)Av + (size_t)arow * 128 + q * 8;
        a0 = *(const half8*)(ap);
        a1 = *(const half8*)(ap + 32);
        a2 = *(const half8*)(ap + 64);
        a3 = *(const half8*)(ap + 96);
    }

    __syncthreads();

    floatx4 acc[16];
    #pragma unroll
    for (int ct = 0; ct < 16; ++ct) {
        const _Float16* bp = sB + (ct * 16 + ln) * BPAD + q * 8;
        half8 b0 = *(const half8*)(bp);
        half8 b1 = *(const half8*)(bp + 32);
        half8 b2 = *(const half8*)(bp + 64);
        half8 b3 = *(const half8*)(bp + 96);
        floatx4 c = {0.f, 0.f, 0.f, 0.f};
        c = __builtin_amdgcn_mfma_f32_16x16x32_f16(a0, b0, c, 0, 0, 0);
        c = __builtin_amdgcn_mfma_f32_16x16x32_f16(a1, b1, c, 0, 0, 0);
        c = __builtin_amdgcn_mfma_f32_16x16x32_f16(a2, b2, c, 0, 0, 0);
        c = __builtin_amdgcn_mfma_f32_16x16x32_f16(a3, b3, c, 0, 0, 0);
        acc[ct] = c;
    }

    #pragma unroll
    for (int ct = 0; ct < 16; ++ct) {
        int col = ct * 16 + ln;
        #pragma unroll
        for (int r = 0; r < 4; ++r) {
            int grow = row0 + q * 4 + r;
            if (grow < n) {
                _Float16 v = (_Float16)acc[ct][r];
                if (ct < 8) outL[(size_t)grow * 128 + col] = v;
                else        outR[(size_t)grow * 128 + (col - 128)] = v;
            }
        }
    }
}

// ---------------- fused kernels ----------------------------------------------

// fused_pre: blocks 0..127 sortA; blocks 128.. convert weights/att
__global__ __launch_bounds__(256)
void fused_pre(const int* __restrict__ dstA, int* __restrict__ hist_mat,
               int E, int Et, int csz,
               const float* __restrict__ Wl1, const float* __restrict__ Wr1,
               const float* __restrict__ Wl2, const float* __restrict__ Wr2,
               const float* __restrict__ att1, const float* __restrict__ att2,
               _Float16* __restrict__ Wt1, _Float16* __restrict__ Wt2,
               _Float16* __restrict__ attH) {
    if (blockIdx.x < CHUNKS) {
        sortA_body(blockIdx.x, dstA, hist_mat, E, Et, csz);
    } else {
        int t = (blockIdx.x - CHUNKS) * 256 + threadIdx.x;
        convert_body(t, Wl1, Wr1, Wl2, Wr2, att1, att2, Wt1, Wt2, attH);
    }
}

// fused_scan_gemm: block 0 = hist scan (1 block, 256 threads); blocks 1.. =
// first third of layer-1 GEMM (A = fp32 X). Hides the scan under the GEMM.
__global__ __launch_bounds__(256)
void fused_scan_gemm(const int* __restrict__ hist_mat, int* __restrict__ offs_flat,
                     const float* __restrict__ X, const _Float16* __restrict__ Wt1,
                     _Float16* __restrict__ outL, _Float16* __restrict__ outR, int n) {
    __shared__ _Float16 sB[256 * BPAD];
    if (blockIdx.x == 0) {
        scan256_body(hist_mat, offs_flat);
    } else {
        gemm_body<true>(blockIdx.x - 1, X, Wt1, outL, outR, n, sB);
    }
}

// fused_mid: blocks 0..127 sortC; blocks 128.. second third of layer-1 GEMM
__global__ __launch_bounds__(256)
void fused_mid(const int* __restrict__ srcA, const int* __restrict__ dstA,
               const int* __restrict__ offs_flat, int* __restrict__ packed,
               int E, int Et, int csz, int gemm_base,
               const float* __restrict__ X, const _Float16* __restrict__ Wt1,
               _Float16* __restrict__ outL, _Float16* __restrict__ outR, int n) {
    __shared__ _Float16 sB[256 * BPAD];
    if (blockIdx.x < CHUNKS) {
        sortC_body(blockIdx.x, srcA, dstA, offs_flat, packed, E, Et, csz);
    } else {
        gemm_body<true>(blockIdx.x - CHUNKS + gemm_base, X, Wt1, outL, outR, n, sB);
    }
}

// fused_sortD_gemm: blocks 0..nbuck-1 fine sort; blocks nbuck.. = last third of
// layer-1 GEMM. Dynamic-LDS union (69632B) keeps occupancy at 2 blocks/CU.
__global__ __launch_bounds__(256)
void fused_sortD_gemm(const int* __restrict__ offs_flat, const int* __restrict__ packed,
                      int* __restrict__ rowptr, int* __restrict__ srcs,
                      int n, int Et, int nbuck, int gemm_base,
                      const float* __restrict__ X, const _Float16* __restrict__ Wt1,
                      _Float16* __restrict__ outL, _Float16* __restrict__ outR) {
    extern __shared__ char smem[];
    if (blockIdx.x < nbuck) {
        sortD_body(blockIdx.x, offs_flat, packed, rowptr, srcs, n, Et, nbuck, smem);
    } else {
        gemm_body<true>(blockIdx.x - nbuck + gemm_base, X, Wt1, outL, outR, n,
                        (_Float16*)smem);
    }
}

// layer-2 GEMM standalone
__global__ __launch_bounds__(256)
void gemm_l2(const _Float16* __restrict__ A, const _Float16* __restrict__ Bt,
             _Float16* __restrict__ outL, _Float16* __restrict__ outR, int n) {
    __shared__ _Float16 sB[256 * BPAD];
    gemm_body<false>(blockIdx.x, A, Bt, outL, outR, n, sB);
}

// ---------------- edge aggregation: quadrant-per-edge, 4-deep MLP ------------
// Wave = 4 quadrants x 16 lanes; quadrant q handles one edge per proc; lane ln
// holds channels ln*8..+7 (16B gathers). 16-edge inner step = 4 independent
// gathers in flight. leaky+dot packed fp16 + v_dot2_f32_f16; DPP reduction.

template <bool LAYER1>
__global__ __launch_bounds__(256)
void edge_aggregate(const _Float16* __restrict__ xl, const _Float16* __restrict__ xr,
                    const _Float16* __restrict__ attH, const float* __restrict__ bias,
                    const int* __restrict__ rowptr, const int* __restrict__ srcs,
                    void* __restrict__ outv, int n) {
    int node = blockIdx.x * (blockDim.x >> 6) + (threadIdx.x >> 6);
    int lane = threadIdx.x & 63;
    if (node >= n) return;
    int ln = lane & 15;
    int q  = lane >> 4;
    int c0 = ln * 8;

    half8 xrh = *(const half8*)(xr + (size_t)node * 128 + c0);
    half8 ahh = *(const half8*)(attH + c0);

    float acc[8] = {0.f, 0.f, 0.f, 0.f, 0.f, 0.f, 0.f, 0.f};
    float l = 0.f;

    auto proc = [&](half8 vh, bool valid) {
        half8 e  = vh + xrh;                                   // pk_add x4
        half8 es = e * (_Float16)NEG_SLOPE;                    // pk_mul x4
        half8 lr = __builtin_elementwise_max(e, es);           // pk_max x4
        float p = 0.f;
        #pragma unroll
        for (int k = 0; k < 4; ++k) {
            half2v ee = { lr[2 * k], lr[2 * k + 1] };
            half2v aa = { ahh[2 * k], ahh[2 * k + 1] };
#ifdef HAVE_FDOT2
            p = __builtin_amdgcn_fdot2(ee, aa, p, false);      // v_dot2_f32_f16
#else
            p = fmaf((float)ee[0], (float)aa[0], p);
            p = fmaf((float)ee[1], (float)aa[1], p);
#endif
        }
        p += dppmov<DPP_XOR1>(p);
        p += dppmov<DPP_XOR2>(p);
        if (!LAYER1) { p += dppmov<DPP_HMIRR>(p); p += dppmov<DPP_MIRR>(p); }
        float pe = __expf(p);
        if (!valid) pe = 0.f;
        l += pe;
        #pragma unroll
        for (int k = 0; k < 8; ++k) acc[k] = fmaf(pe, (float)vh[k], acc[k]);
    };

    int jb = rowptr[node], je = rowptr[node + 1];
    for (int base = jb; base < je; base += 64) {
        int idx = base + lane;
        int myS = (idx < je) ? srcs[idx] : 0;
        int cnt = min(64, je - base);
        int t = 0;
        for (; t + 16 <= cnt; t += 16) {
            int s0 = __shfl(myS, t + q, 64);
            int s1 = __shfl(myS, t + 4 + q, 64);
            int s2 = __shfl(myS, t + 8 + q, 64);
            int s3 = __shfl(myS, t + 12 + q, 64);
            half8 v0 = *(const half8*)(xl + (size_t)s0 * 128 + c0);
            half8 v1 = *(const half8*)(xl + (size_t)s1 * 128 + c0);
            half8 v2 = *(const half8*)(xl + (size_t)s2 * 128 + c0);
            half8 v3 = *(const half8*)(xl + (size_t)s3 * 128 + c0);
            proc(v0, true); proc(v1, true); proc(v2, true); proc(v3, true);
        }
        for (; t < cnt; t += 4) {
            int sa = __shfl(myS, t + q, 64);
            half8 va = *(const half8*)(xl + (size_t)sa * 128 + c0);
            proc(va, (t + q) < cnt);
        }
    }

    // merge the 4 quadrant partials
    #pragma unroll
    for (int k = 0; k < 8; ++k) {
        acc[k] += __shfl_xor(acc[k], 16, 64);
        acc[k] += __shfl_xor(acc[k], 32, 64);
    }
    l += __shfl_xor(l, 16, 64);
    l += __shfl_xor(l, 32, 64);

    float inv = 1.0f / l;            // self loop guarantees l > 0
    float bv[8];
    *(float4*)&bv[0] = *(const float4*)(bias + c0);
    *(float4*)&bv[4] = *(const float4*)(bias + c0 + 4);
    float o[8];
    #pragma unroll
    for (int k = 0; k < 8; ++k) {
        o[k] = acc[k] * inv + bv[k];
        if (LAYER1) o[k] = fmaxf(o[k], 0.f);
    }
    if (lane < 16) {
        if (LAYER1) {
            __half2 hh2[4];
            #pragma unroll
            for (int k = 0; k < 4; ++k) hh2[k] = __floats2half2_rn(o[2 * k], o[2 * k + 1]);
            *(float4*)((_Float16*)outv + (size_t)node * 128 + c0) = *(float4*)&hh2[0];
        } else {
            float* out = (float*)outv;
            *(float4*)(out + (size_t)node * 128 + c0)     = *(float4*)&o[0];
            *(float4*)(out + (size_t)node * 128 + c0 + 4) = *(float4*)&o[4];
        }
    }
}

// ---------------- launch -----------------------------------------------------

extern "C" void kernel_launch(void* const* d_in, const int* in_sizes, int n_in,
                              void* d_out, int out_size, void* d_ws, size_t ws_size,
                              hipStream_t stream) {
    const float* x    = (const float*)d_in[0];
    const int*   ei   = (const int*)d_in[1];   // [2,E] int32
    const float* Wl1  = (const float*)d_in[2];
    const float* Wr1  = (const float*)d_in[3];
    const float* att1 = (const float*)d_in[4]; // [4,32] -> flat 128
    const float* b1   = (const float*)d_in[5];
    const float* Wl2  = (const float*)d_in[6];
    const float* Wr2  = (const float*)d_in[7];
    const float* att2 = (const float*)d_in[8]; // [1,128]
    const float* b2   = (const float*)d_in[9];

    int n  = in_sizes[0] / 128;
    int E  = in_sizes[1] / 2;
    int Et = E + n;                  // with self loops

    _Float16* xlh  = (_Float16*)d_ws;               // [n,128]
    _Float16* xrh2 = xlh + (size_t)n * 128;         // [n,128]
    _Float16* hh   = xrh2 + (size_t)n * 128;        // [n,128]
    _Float16* Wt1  = hh  + (size_t)n * 128;         // [256,128]
    _Float16* Wt2  = Wt1 + 256 * 128;               // [256,128]
    _Float16* attH = Wt2 + 256 * 128;               // [2][128]
    int* rowptr   = (int*)(attH + 256);             // [n+1] (padded to 16B)
    int* srcs     = rowptr + ((n + 4) & ~3);        // [Et], 16B aligned
    int* packed   = srcs + Et;                      // [Et]
    int* hist_mat = packed + Et;                    // [256*128] bucket-major
    int* offs_flat= hist_mat + CHUNKS * 256;        // [256*128] flat f-order

    const int* srcA = ei;
    const int* dstA = ei + E;

    int csz   = (Et + CHUNKS - 1) / CHUNKS;
    int nbuck = (n + 255) >> 8;
    int gemm_grid = (n + 63) / 64;
    int edge_grid = (n + 3) / 4;
    int GA = gemm_grid / 3;                // gemm1 third in scan kernel
    int GB = gemm_grid / 3;                // gemm1 third in sortC kernel
    int GC = gemm_grid - GA - GB;          // gemm1 third in sortD kernel

    // 1: sortA (coarse hist, bucket-major) || weight/att converts
    fused_pre<<<CHUNKS + 257, 256, 0, stream>>>(
        dstA, hist_mat, E, Et, csz,
        Wl1, Wr1, Wl2, Wr2, att1, att2, Wt1, Wt2, attH);
    // 2: hist scan (1 block) || layer-1 GEMM 1/3
    fused_scan_gemm<<<1 + GA, 256, 0, stream>>>(
        hist_mat, offs_flat, x, Wt1, xlh, xrh2, n);
    // 3: sortC (coarse scatter) || layer-1 GEMM 2/3
    fused_mid<<<CHUNKS + GB, 256, 0, stream>>>(
        srcA, dstA, offs_flat, packed, E, Et, csz, GA,
        x, Wt1, xlh, xrh2, n);
    // 4: sortD (per-bucket fine sort) || layer-1 GEMM 3/3 (dynamic-LDS union)
    fused_sortD_gemm<<<nbuck + GC, 256, GEMM_LDS_BYTES, stream>>>(
        offs_flat, packed, rowptr, srcs, n, Et, nbuck, GA + GB,
        x, Wt1, xlh, xrh2);
    // 5: layer-1 aggregation -> hh (fp16)
    edge_aggregate<true><<<edge_grid, 256, 0, stream>>>(
        xlh, xrh2, attH, b1, rowptr, srcs, hh, n);
    // 6: layer-2 GEMM
    gemm_l2<<<gemm_grid, 256, 0, stream>>>(hh, Wt2, xlh, xrh2, n);
    // 7: layer-2 aggregation -> d_out (fp32)
    edge_aggregate<false><<<edge_grid, 256, 0, stream>>>(
        xlh, xrh2, attH + 128, b2, rowptr, srcs, d_out, n);
}